// Round 2
// baseline (588.630 us; speedup 1.0000x reference)
//
#include <hip/hip_runtime.h>

typedef unsigned int u32;
typedef unsigned short u16;

// B=16, N=4096, IN=192, TD=64, H=4, D=16, FFN=128, OUT=192
#define NB 16
#define NN 4096
#define IND 192
#define TD 64
#define ROWS1 32

__device__ __forceinline__ float bf2f(u16 u) {
  union { u32 i; float f; } c; c.i = ((u32)u) << 16; return c.f;
}
__device__ __forceinline__ float lo16(u32 u) {
  union { u32 i; float f; } c; c.i = u << 16; return c.f;
}
__device__ __forceinline__ float hi16(u32 u) {
  union { u32 i; float f; } c; c.i = u & 0xffff0000u; return c.f;
}
__device__ __forceinline__ u16 f2bf(float f) {
  union { float f; u32 i; } c; c.f = f;
  u32 r = c.i + 0x7fffu + ((c.i >> 16) & 1u);  // round-to-nearest-even
  return (u16)(r >> 16);
}

__device__ __forceinline__ float ln64(float y, float g, float be) {
  float s = y, sq = y * y;
  #pragma unroll
  for (int off = 32; off > 0; off >>= 1) {
    s  += __shfl_xor(s, off, 64);
    sq += __shfl_xor(sq, off, 64);
  }
  float mu  = s * 0.015625f;
  float var = sq * 0.015625f - mu * mu;
  return (y - mu) * rsqrtf(var + 1e-5f) * g + be;
}

// dtype-generic loads
template<bool F32> __device__ __forceinline__ float ldw(const void* p, int idx) {
  if constexpr (F32) return ((const float*)p)[idx];
  else return bf2f(((const u16*)p)[idx]);
}
template<bool F32> __device__ __forceinline__ void ldx8(const void* xp, size_t row,
                                                        int i0, float xf[8]) {
  if constexpr (F32) {
    const float* base = (const float*)xp + row * IND + i0;
    float4 a = *reinterpret_cast<const float4*>(base);
    float4 b = *reinterpret_cast<const float4*>(base + 4);
    xf[0]=a.x; xf[1]=a.y; xf[2]=a.z; xf[3]=a.w;
    xf[4]=b.x; xf[5]=b.y; xf[6]=b.z; xf[7]=b.w;
  } else {
    uint4 v = *reinterpret_cast<const uint4*>((const u32*)xp + row * 96 + (i0 >> 1));
    xf[0]=lo16(v.x); xf[1]=hi16(v.x); xf[2]=lo16(v.y); xf[3]=hi16(v.y);
    xf[4]=lo16(v.z); xf[5]=hi16(v.z); xf[6]=lo16(v.w); xf[7]=hi16(v.w);
  }
}

// ---------------- Kernel 0: dtype detection ----------------
// fp32 data read as bf16 pairs -> low halves have random exponents -> huge/NaN.
__global__ __launch_bounds__(64) void k_detect(const u32* __restrict__ x2,
                                               int* __restrict__ flag) {
  int t = threadIdx.x;
  int bad = 0;
  for (int i = 0; i < 16; ++i) {
    float a = fabsf(lo16(x2[t * 16 + i]));
    if (!(a < 1e4f)) bad = 1;          // catches inf/nan/huge
  }
  int anybad = __any(bad);
  if (t == 0) *flag = anybad ? 1 : 0;  // 1 = fp32, 0 = bf16
}

// ---------------- Kernel 1: QKV projection + attention stats ----------------
// stats layout per (b,h) [832 floats]:
//   [0..255] fkv_k1, [256..511] fkv_k2, [512..767] fkv_k3  (f*16+c)
//   [768..815] sumK k1,k2,k3 (16 each), [816..831] sumV
template<bool F32> __device__ void qkv_body(
    const void* x, const void* Wq, const void* bq,
    const void* Wk, const void* bk, const void* Wv, const void* bv,
    float* wsQ, float* stats, float (*Ks)[64], float (*Vs)[64])
{
  const int tid  = threadIdx.x;
  const int w    = tid >> 6;       // 0=Q, 1=K, 2=V
  const int lane = tid & 63;
  const int rowbase = blockIdx.x * ROWS1;
  const int b = rowbase >> 12;

  const void* W    = (w == 0) ? Wq : (w == 1) ? Wk : Wv;
  const void* bias = (w == 0) ? bq : (w == 1) ? bk : bv;

  float acc[ROWS1];
  {
    float b0 = ldw<F32>(bias, lane);
    #pragma unroll
    for (int r = 0; r < ROWS1; ++r) acc[r] = b0;
  }

  for (int i0 = 0; i0 < IND; i0 += 8) {
    float wv[8];
    #pragma unroll
    for (int k = 0; k < 8; ++k) wv[k] = ldw<F32>(W, (i0 + k) * TD + lane);
    #pragma unroll
    for (int r = 0; r < ROWS1; ++r) {
      float xf[8];
      ldx8<F32>(x, (size_t)(rowbase + r), i0, xf);
      #pragma unroll
      for (int k = 0; k < 8; ++k) acc[r] = fmaf(xf[k], wv[k], acc[r]);
    }
  }

  if (w == 0) {
    #pragma unroll
    for (int r = 0; r < ROWS1; ++r)
      wsQ[(size_t)(rowbase + r) * TD + lane] = acc[r];
  } else if (w == 1) {
    #pragma unroll
    for (int r = 0; r < ROWS1; ++r) Ks[r][lane] = acc[r];
  } else {
    #pragma unroll
    for (int r = 0; r < ROWS1; ++r) Vs[r][lane] = acc[r];
  }
  __syncthreads();

  float* sb = stats + (size_t)(b * 4) * 832;

  for (int item = tid; item < 1024; item += 192) {
    const int h = item >> 8, f = (item >> 4) & 15, c = item & 15;
    float a1 = 0.f, a2 = 0.f, a3 = 0.f;
    #pragma unroll
    for (int r = 0; r < ROWS1; ++r) {
      float kv  = Ks[r][h * 16 + f];
      float vv  = Vs[r][h * 16 + c];
      float kv2 = kv * kv;
      a1 = fmaf(kv,       vv, a1);
      a2 = fmaf(kv2,      vv, a2);
      a3 = fmaf(kv2 * kv, vv, a3);
    }
    float* base = sb + (size_t)h * 832 + f * 16 + c;
    atomicAdd(base +   0, a1);
    atomicAdd(base + 256, a2);
    atomicAdd(base + 512, a3);
  }

  {
    const int kk = tid >> 6;
    const int hf = tid & 63;
    const int h = hf >> 4, f = hf & 15;
    float s = 0.f;
    #pragma unroll
    for (int r = 0; r < ROWS1; ++r) {
      float kv = Ks[r][hf];
      float p  = (kk == 0) ? kv : (kk == 1) ? kv * kv : kv * kv * kv;
      s += p;
    }
    atomicAdd(sb + (size_t)h * 832 + 768 + kk * 16 + f, s);
    if (tid < 64) {
      float sv = 0.f;
      #pragma unroll
      for (int r = 0; r < ROWS1; ++r) sv += Vs[r][hf];
      atomicAdd(sb + (size_t)h * 832 + 816 + f, sv);
    }
  }
}

__global__ __launch_bounds__(192) void k_qkv_stats(
    const int* __restrict__ flag, const void* x,
    const void* Wq, const void* bq, const void* Wk, const void* bk,
    const void* Wv, const void* bv, float* wsQ, float* stats)
{
  __shared__ float Ks[ROWS1][64];
  __shared__ float Vs[ROWS1][64];
  if (*flag) qkv_body<true >(x, Wq, bq, Wk, bk, Wv, bv, wsQ, stats, Ks, Vs);
  else       qkv_body<false>(x, Wq, bq, Wk, bk, Wv, bv, wsQ, stats, Ks, Vs);
}

// ---------------- Kernel 2: finalize coefficient matrices ----------------
// M layout per (b,h) [784 floats]: M1[256], M2[256], M3[256], c0[16]
template<bool F32> __device__ void finalize_body(
    const float* stats, const void* Pi, float* M)
{
  const int bh = blockIdx.x;
  const int h  = bh & 3;
  const float* sb = stats + (size_t)bh * 832;
  float* mb = M + (size_t)bh * 784;
  const int t = threadIdx.x;
  const float inv6 = 1.0f / 6.0f;

  {
    const int f = t >> 4, c = t & 15;
    #pragma unroll
    for (int k = 0; k < 3; ++k) {
      float fkv = sb[k * 256 + f * 16 + c];
      float sk  = sb[768 + k * 16 + f];
      float pi  = ldw<F32>(Pi, h * 4 + (k + 1));
      mb[k * 256 + f * 16 + c] = fkv / ((sk + 1e-8f) * 4.0f) * pi * inv6;
    }
  }
  if (t < 16) {
    float sv  = sb[816 + t];
    float pi0 = ldw<F32>(Pi, h * 4 + 0);
    mb[768 + t] = sv / (4096.0f + 1e-8f) * pi0 * inv6;
  }
}

__global__ __launch_bounds__(256) void k_finalize(
    const int* __restrict__ flag, const float* __restrict__ stats,
    const void* Pi, float* __restrict__ M)
{
  if (*flag) finalize_body<true >(stats, Pi, M);
  else       finalize_body<false>(stats, Pi, M);
}

// ---------------- Kernel 3: fused attention-out + LN + FFN + LN + out ------
template<bool F32> __device__ void fused_body(
    const void* x, const float* wsQ, const float* M,
    const void* Win, const void* Wout, const void* bout,
    const void* W1, const void* b1, const void* W2, const void* b2,
    const void* lng, const void* lnb, const void* Wp, void* out)
{
  const int tid = threadIdx.x;
  const int ww  = tid >> 6;
  const int j   = tid & 63;
  const int g0  = blockIdx.x * 16 + ww * 4;
  const int b   = g0 >> 12;
  const int n2  = g0 & 4095;
  const int h   = n2 >> 10;
  const float* mb = M + (size_t)((b << 2) + h) * 784;
  const int sub = j >> 4;
  const int d   = j & 15;

  // ---- attention output ----
  float att[4];
  {
    float c0 = mb[768 + d];
    #pragma unroll
    for (int r = 0; r < 4; ++r) {
      const int qrow = (((n2 + r) & 1023) << 2) + sub;
      const float* qp = wsQ + (size_t)((b << 12) + qrow) * TD + (h << 4);
      float4 qa = *reinterpret_cast<const float4*>(qp + 0);
      float4 qb = *reinterpret_cast<const float4*>(qp + 4);
      float4 qc = *reinterpret_cast<const float4*>(qp + 8);
      float4 qd = *reinterpret_cast<const float4*>(qp + 12);
      float q[16] = {qa.x, qa.y, qa.z, qa.w, qb.x, qb.y, qb.z, qb.w,
                     qc.x, qc.y, qc.z, qc.w, qd.x, qd.y, qd.z, qd.w};
      float a = c0;
      #pragma unroll
      for (int f = 0; f < 16; ++f) {
        float qv = q[f];
        float q2 = qv * qv;
        a = fmaf(qv,      mb[      f * 16 + d], a);
        a = fmaf(q2,      mb[256 + f * 16 + d], a);
        a = fmaf(q2 * qv, mb[512 + f * 16 + d], a);
      }
      att[r] = a;
    }
  }

  // ---- proj = x @ Win (no bias) ----
  float p[4] = {0.f, 0.f, 0.f, 0.f};
  for (int i0 = 0; i0 < IND; i0 += 8) {
    float wv[8];
    #pragma unroll
    for (int k = 0; k < 8; ++k) wv[k] = ldw<F32>(Win, (i0 + k) * TD + j);
    #pragma unroll
    for (int r = 0; r < 4; ++r) {
      float xf[8];
      ldx8<F32>(x, (size_t)(g0 + r), i0, xf);
      #pragma unroll
      for (int k = 0; k < 8; ++k) p[r] = fmaf(xf[k], wv[k], p[r]);
    }
  }

  const float gj = ldw<F32>(lng, j), bj = ldw<F32>(lnb, j);
  float res1[4];
  #pragma unroll
  for (int r = 0; r < 4; ++r) res1[r] = ln64(p[r] + att[r], gj, bj);

  // ---- FFN layer 1 ----
  float h1[4], h2[4];
  {
    float a1 = ldw<F32>(b1, j), a2 = ldw<F32>(b1, j + 64);
    #pragma unroll
    for (int r = 0; r < 4; ++r) { h1[r] = a1; h2[r] = a2; }
  }
  for (int i = 0; i < 64; ++i) {
    float w1a = ldw<F32>(W1, i * 128 + j);
    float w1b = ldw<F32>(W1, i * 128 + j + 64);
    #pragma unroll
    for (int r = 0; r < 4; ++r) {
      float rv = __shfl(res1[r], i, 64);
      h1[r] = fmaf(rv, w1a, h1[r]);
      h2[r] = fmaf(rv, w1b, h2[r]);
    }
  }
  #pragma unroll
  for (int r = 0; r < 4; ++r) {
    h1[r] = fmaxf(h1[r], 0.f);
    h2[r] = fmaxf(h2[r], 0.f);
  }

  // ---- FFN layer 2 ----
  float o[4];
  {
    float bb = ldw<F32>(b2, j);
    #pragma unroll
    for (int r = 0; r < 4; ++r) o[r] = bb;
  }
  for (int c = 0; c < 64; ++c) {
    float w2a = ldw<F32>(W2, c * TD + j);
    float w2b = ldw<F32>(W2, (c + 64) * TD + j);
    #pragma unroll
    for (int r = 0; r < 4; ++r) {
      o[r] = fmaf(__shfl(h1[r], c, 64), w2a, o[r]);
      o[r] = fmaf(__shfl(h2[r], c, 64), w2b, o[r]);
    }
  }
  float res2[4];
  #pragma unroll
  for (int r = 0; r < 4; ++r) res2[r] = ln64(res1[r] + o[r], gj, bj);

  // ---- out = res2 @ Wout + bout + x @ weights_pool ----
  float o0[4], o1[4], o2[4];
  {
    float c0_ = ldw<F32>(bout, j), c1_ = ldw<F32>(bout, j + 64),
          c2_ = ldw<F32>(bout, j + 128);
    #pragma unroll
    for (int r = 0; r < 4; ++r) { o0[r] = c0_; o1[r] = c1_; o2[r] = c2_; }
  }
  for (int i = 0; i < 64; ++i) {
    float wa = ldw<F32>(Wout, i * 192 + j);
    float wb = ldw<F32>(Wout, i * 192 + j + 64);
    float wc = ldw<F32>(Wout, i * 192 + j + 128);
    #pragma unroll
    for (int r = 0; r < 4; ++r) {
      float rv = __shfl(res2[r], i, 64);
      o0[r] = fmaf(rv, wa, o0[r]);
      o1[r] = fmaf(rv, wb, o1[r]);
      o2[r] = fmaf(rv, wc, o2[r]);
    }
  }
  for (int i0 = 0; i0 < IND; i0 += 8) {
    float wa[8], wb[8], wc[8];
    #pragma unroll
    for (int k = 0; k < 8; ++k) {
      wa[k] = ldw<F32>(Wp, (i0 + k) * 192 + j);
      wb[k] = ldw<F32>(Wp, (i0 + k) * 192 + j + 64);
      wc[k] = ldw<F32>(Wp, (i0 + k) * 192 + j + 128);
    }
    #pragma unroll
    for (int r = 0; r < 4; ++r) {
      float xf[8];
      ldx8<F32>(x, (size_t)(g0 + r), i0, xf);
      #pragma unroll
      for (int k = 0; k < 8; ++k) {
        o0[r] = fmaf(xf[k], wa[k], o0[r]);
        o1[r] = fmaf(xf[k], wb[k], o1[r]);
        o2[r] = fmaf(xf[k], wc[k], o2[r]);
      }
    }
  }

  #pragma unroll
  for (int r = 0; r < 4; ++r) {
    if constexpr (F32) {
      float* op = (float*)out + (size_t)(g0 + r) * 192;
      op[j]       = o0[r];
      op[j + 64]  = o1[r];
      op[j + 128] = o2[r];
    } else {
      u16* op = (u16*)out + (size_t)(g0 + r) * 192;
      op[j]       = f2bf(o0[r]);
      op[j + 64]  = f2bf(o1[r]);
      op[j + 128] = f2bf(o2[r]);
    }
  }
}

__global__ __launch_bounds__(256) void k_fused(
    const int* __restrict__ flag,
    const void* x, const float* __restrict__ wsQ, const float* __restrict__ M,
    const void* Win, const void* Wout, const void* bout,
    const void* W1, const void* b1, const void* W2, const void* b2,
    const void* lng, const void* lnb, const void* Wp, void* out)
{
  if (*flag) fused_body<true >(x, wsQ, M, Win, Wout, bout, W1, b1, W2, b2,
                               lng, lnb, Wp, out);
  else       fused_body<false>(x, wsQ, M, Win, Wout, bout, W1, b1, W2, b2,
                               lng, lnb, Wp, out);
}

extern "C" void kernel_launch(void* const* d_in, const int* in_sizes, int n_in,
                              void* d_out, int out_size, void* d_ws, size_t ws_size,
                              hipStream_t stream)
{
  const void* x   = d_in[0];
  const void* Wq  = d_in[1];
  const void* bq  = d_in[2];
  const void* Wk  = d_in[3];
  const void* bk  = d_in[4];
  const void* Wv  = d_in[5];
  const void* bv  = d_in[6];
  const void* Win = d_in[7];
  const void* Wout= d_in[8];
  const void* bout= d_in[9];
  const void* W1  = d_in[10];
  const void* b1  = d_in[11];
  const void* W2  = d_in[12];
  const void* b2  = d_in[13];
  const void* lng = d_in[14];
  const void* lnb = d_in[15];
  const void* Wp  = d_in[16];
  const void* Pi  = d_in[17];

  float* wsQ   = (float*)d_ws;                          // 16*4096*64 floats
  float* stats = wsQ + (size_t)NB * NN * TD;            // 64*832 floats
  float* Mm    = stats + (size_t)64 * 832;              // 64*784 floats
  int*   flag  = (int*)(Mm + (size_t)64 * 784);

  k_detect<<<1, 64, 0, stream>>>((const u32*)x, flag);
  hipMemsetAsync(stats, 0, (size_t)64 * 832 * sizeof(float), stream);

  k_qkv_stats<<<(NB * NN) / ROWS1, 192, 0, stream>>>(
      flag, x, Wq, bq, Wk, bk, Wv, bv, wsQ, stats);
  k_finalize<<<64, 256, 0, stream>>>(flag, stats, Pi, Mm);
  k_fused<<<(NB * NN) / 16, 256, 0, stream>>>(
      flag, x, wsQ, Mm, Win, Wout, bout, W1, b1, W2, b2, lng, lnb, Wp, d_out);
}

// Round 4
// 295.185 us; speedup vs baseline: 1.9941x; 1.9941x over previous
//
#include <hip/hip_runtime.h>

typedef unsigned int u32;
typedef unsigned short u16;

#define NB 16
#define NN 4096
#define IND 192

typedef __attribute__((ext_vector_type(8))) short short8;
typedef __attribute__((ext_vector_type(4))) float f32x4;
#define MFMA16 __builtin_amdgcn_mfma_f32_16x16x32_bf16

__device__ __forceinline__ float bf2f(u16 u) {
  union { u32 i; float f; } c; c.i = ((u32)u) << 16; return c.f;
}
__device__ __forceinline__ float lo16(u32 u) {
  union { u32 i; float f; } c; c.i = u << 16; return c.f;
}
__device__ __forceinline__ float hi16(u32 u) {
  union { u32 i; float f; } c; c.i = u & 0xffff0000u; return c.f;
}
__device__ __forceinline__ u16 f2bf(float f) {
  union { float f; u32 i; } c; c.f = f;
  u32 r = c.i + 0x7fffu + ((c.i >> 16) & 1u);  // RNE
  return (u16)(r >> 16);
}
__device__ __forceinline__ float ldwf(const void* p, int i, int isf) {
  return isf ? ((const float*)p)[i] : bf2f(((const u16*)p)[i]);
}
__device__ __forceinline__ short8 ld_frag8(const u16* p) {
  union { uint4 u; short8 s; } c;
  c.u = *reinterpret_cast<const uint4*>(p);
  return c.s;
}
__device__ __forceinline__ float ln64(float y, float g, float be) {
  float s = y, sq = y * y;
  #pragma unroll
  for (int off = 32; off > 0; off >>= 1) {
    s  += __shfl_xor(s, off, 64);
    sq += __shfl_xor(sq, off, 64);
  }
  float mu  = s * 0.015625f;
  float var = sq * 0.015625f - mu * mu;
  return (y - mu) * rsqrtf(var + 1e-5f) * g + be;
}

// ---------------- dtype detect ----------------
__global__ __launch_bounds__(64) void k_detect(const u32* __restrict__ x2,
                                               int* __restrict__ flag) {
  int t = threadIdx.x;
  int bad = 0;
  for (int i = 0; i < 16; ++i) {
    float a = fabsf(lo16(x2[t * 16 + i]));
    if (!(a < 1e4f)) bad = 1;
  }
  int anybad = __any(bad);
  if (t == 0) *flag = anybad ? 1 : 0;   // 1 = fp32 inputs
}

// ---------------- x -> bf16 ----------------
__global__ __launch_bounds__(256) void k_xb(const int* __restrict__ flag,
                                            const void* __restrict__ x,
                                            u16* __restrict__ xb) {
  const int isf = *flag;
  size_t gid = (size_t)blockIdx.x * 256 + threadIdx.x;
  if (isf) {
    const float4* src = (const float4*)x;
    for (size_t i = gid; i < 3145728; i += 1048576) {
      float4 v = src[i];
      ushort4 o;
      o.x = f2bf(v.x); o.y = f2bf(v.y); o.z = f2bf(v.z); o.w = f2bf(v.w);
      ((ushort4*)xb)[i] = o;
    }
  } else {
    const uint4* src = (const uint4*)x;
    for (size_t i = gid; i < 1572864; i += 1048576)
      ((uint4*)xb)[i] = src[i];
  }
}

// ---------------- per-batch column sums of x (fp32 exact) ----------------
__global__ __launch_bounds__(192) void k_xsum(const int* __restrict__ flag,
                                              const void* __restrict__ x,
                                              float* __restrict__ xsum) {
  const int isf = *flag;
  const int t = threadIdx.x;
  const int r0 = blockIdx.x * 256;
  const int b = r0 >> 12;
  float s = 0.f;
  if (isf) {
    const float* xp = (const float*)x;
    for (int r = 0; r < 256; ++r) s += xp[(size_t)(r0 + r) * 192 + t];
  } else {
    const u16* xp = (const u16*)x;
    for (int r = 0; r < 256; ++r) s += bf2f(xp[(size_t)(r0 + r) * 192 + t]);
  }
  atomicAdd(xsum + b * 192 + t, s);
}

// ---------------- build swizzled B operands ----------------
// Bs1:   [ks(6)][nt(16)][lane(64)][e(8)]  over [Wq|Wk|Wv|Win] (192x256), hi
// BsKlo: [ks(6)][nt'(4)][lane(64)][e(8)]  Wk lo-part (cols 64..127)
// Bs2:   [ks(8)][nt(12)][lane(64)][e(8)]  over [Wout;Wp] (256x192)
__global__ __launch_bounds__(256) void k_prepw(
    const int* __restrict__ flag,
    const void* Wq, const void* Wk, const void* Wv, const void* Win,
    const void* Wout, const void* Wp,
    const void* bq, const void* bk, const void* bv,
    u16* __restrict__ Bs1, u16* __restrict__ BsKlo,
    u16* __restrict__ Bs2, float* __restrict__ bcat)
{
  const int isf = *flag;
  int idx = blockIdx.x * 256 + threadIdx.x;
  if (idx < 49152) {
    int e = idx & 7, l = (idx >> 3) & 63, g = idx >> 9;
    int nt = g & 15, ks = g >> 4;
    int k = ks * 32 + (l >> 4) * 8 + e;
    int n = nt * 16 + (l & 15);
    const void* W = (n < 64) ? Wq : (n < 128) ? Wk : (n < 192) ? Wv : Win;
    Bs1[idx] = f2bf(ldwf(W, k * 64 + (n & 63), isf));
  } else if (idx < 61440) {
    int j = idx - 49152;
    int e = j & 7, l = (j >> 3) & 63, g = j >> 9;   // g in 0..23
    int ntp = g & 3, ks = g >> 2;
    int k = ks * 32 + (l >> 4) * 8 + e;
    int n = ntp * 16 + (l & 15);                    // Wk col 0..63
    float wv = ldwf(Wk, k * 64 + n, isf);
    u16 hi = f2bf(wv);
    BsKlo[j] = f2bf(wv - bf2f(hi));
  } else if (idx < 110592) {
    int j = idx - 61440;
    int e = j & 7, l = (j >> 3) & 63, g = j >> 9;
    int nt = g % 12, ks = g / 12;
    int k = ks * 32 + (l >> 4) * 8 + e;
    int n = nt * 16 + (l & 15);
    float v = (k < 64) ? ldwf(Wout, k * 192 + n, isf)
                       : ldwf(Wp, (k - 64) * 192 + n, isf);
    Bs2[j] = f2bf(v);
  } else if (idx < 110848) {
    int n = idx - 110592;
    bcat[n] = (n < 64)  ? ldwf(bq, n, isf)
            : (n < 128) ? ldwf(bk, n - 64, isf)
            : (n < 192) ? ldwf(bv, n - 128, isf) : 0.f;
  }
}

// ---------------- GEMM1 fused with stats ----------------
// 32 rows/block, 512 threads = 8 waves, 2 n-tiles each:
//   waves 0,1: Q (nt 0..3, 1-term) -> C1 cols 0..63 (bf16)
//   waves 2,3: K (nt 4..7, 4-term split = fp32-accurate) -> LDS Ks (fp32)
//   waves 4,5: V (nt 8..11, 1-term) -> LDS Vs
//   waves 6,7: proj (nt 12..15, 1-term) -> C1 cols 64..127 (bf16)
// then block-level stats reduction (f_kv k=1..3, sumK, sumV) with atomics.
template<bool F32>
__device__ void gemm1_body(const void* __restrict__ x,
                           const u16* __restrict__ Bs1,
                           const u16* __restrict__ BsKlo,
                           const float* __restrict__ bcat,
                           u16* __restrict__ C1, float* __restrict__ stats,
                           float (*xs)[196], float (*Ks)[65], float (*Vs)[65])
{
  const int tid = threadIdx.x;
  const int mbase = blockIdx.x * 32;
  const int b = mbase >> 12;

  if constexpr (F32) {
    for (int i = tid; i < 1536; i += 512) {
      int row = i / 48, c4 = i - row * 48;
      float4 v = *((const float4*)x + (size_t)(mbase + row) * 48 + c4);
      *(float4*)&xs[row][c4 * 4] = v;
    }
  } else {
    for (int i = tid; i < 768; i += 512) {
      int row = i / 24, c8 = i - row * 24;
      uint4 v = *((const uint4*)x + (size_t)(mbase + row) * 24 + c8);
      float* dst = &xs[row][c8 * 8];
      dst[0]=lo16(v.x); dst[1]=hi16(v.x); dst[2]=lo16(v.y); dst[3]=hi16(v.y);
      dst[4]=lo16(v.z); dst[5]=hi16(v.z); dst[6]=lo16(v.w); dst[7]=hi16(v.w);
    }
  }
  __syncthreads();

  const int w = tid >> 6, l = tid & 63, lm = l & 15, lk = l >> 4;
  const int nt0 = w * 2;
  const bool isK = (w == 2) || (w == 3);

  short8 bhi[2][6], blo[2][6];
  #pragma unroll
  for (int n2 = 0; n2 < 2; ++n2)
    #pragma unroll
    for (int ks = 0; ks < 6; ++ks) {
      bhi[n2][ks] = ld_frag8(Bs1 + (size_t)((ks * 16 + nt0 + n2) * 64 + l) * 8);
      if (F32 && isK)
        blo[n2][ks] = ld_frag8(BsKlo + (size_t)((ks * 4 + nt0 + n2 - 4) * 64 + l) * 8);
    }
  float bias[2];
  bias[0] = bcat[nt0 * 16 + lm];
  bias[1] = bcat[(nt0 + 1) * 16 + lm];

  for (int mt = 0; mt < 2; ++mt) {
    short8 ahi[6], alo[6];
    const float* xr = &xs[mt * 16 + lm][0];
    #pragma unroll
    for (int ks = 0; ks < 6; ++ks) {
      float v[8];
      *(float4*)&v[0] = *(const float4*)(xr + ks * 32 + lk * 8);
      *(float4*)&v[4] = *(const float4*)(xr + ks * 32 + lk * 8 + 4);
      short8 h8;
      #pragma unroll
      for (int e = 0; e < 8; ++e) h8[e] = (short)f2bf(v[e]);
      ahi[ks] = h8;
      if (F32 && isK) {
        short8 l8;
        #pragma unroll
        for (int e = 0; e < 8; ++e) {
          float r = v[e] - bf2f((u16)h8[e]);
          l8[e] = (short)f2bf(r);
        }
        alo[ks] = l8;
      }
    }
    f32x4 acc[2];
    #pragma unroll
    for (int n2 = 0; n2 < 2; ++n2) {
      f32x4 a = {bias[n2], bias[n2], bias[n2], bias[n2]};
      acc[n2] = a;
    }
    #pragma unroll
    for (int ks = 0; ks < 6; ++ks)
      #pragma unroll
      for (int n2 = 0; n2 < 2; ++n2) {
        acc[n2] = MFMA16(ahi[ks], bhi[n2][ks], acc[n2], 0, 0, 0);
        if (F32 && isK) {
          acc[n2] = MFMA16(ahi[ks], blo[n2][ks], acc[n2], 0, 0, 0);
          acc[n2] = MFMA16(alo[ks], bhi[n2][ks], acc[n2], 0, 0, 0);
          acc[n2] = MFMA16(alo[ks], blo[n2][ks], acc[n2], 0, 0, 0);
        }
      }
    const int rl = mt * 16 + lk * 4;
    if (w < 2) {
      #pragma unroll
      for (int n2 = 0; n2 < 2; ++n2)
        #pragma unroll
        for (int r = 0; r < 4; ++r)
          C1[(size_t)(mbase + rl + r) * 128 + (nt0 + n2) * 16 + lm] = f2bf(acc[n2][r]);
    } else if (isK) {
      #pragma unroll
      for (int n2 = 0; n2 < 2; ++n2)
        #pragma unroll
        for (int r = 0; r < 4; ++r)
          Ks[rl + r][(nt0 + n2 - 4) * 16 + lm] = acc[n2][r];
    } else if (w < 6) {
      #pragma unroll
      for (int n2 = 0; n2 < 2; ++n2)
        #pragma unroll
        for (int r = 0; r < 4; ++r)
          Vs[rl + r][(nt0 + n2 - 8) * 16 + lm] = acc[n2][r];
    } else {
      #pragma unroll
      for (int n2 = 0; n2 < 2; ++n2)
        #pragma unroll
        for (int r = 0; r < 4; ++r)
          C1[(size_t)(mbase + rl + r) * 128 + 64 + (nt0 + n2 - 12) * 16 + lm] = f2bf(acc[n2][r]);
    }
  }
  __syncthreads();

  // ---- stats ----
  float* sb = stats + (size_t)(b * 4) * 832;
  #pragma unroll
  for (int it = 0; it < 2; ++it) {
    int item = tid + it * 512;
    int hh = item >> 8, f = (item >> 4) & 15, c = item & 15;
    float a1 = 0.f, a2 = 0.f, a3 = 0.f;
    for (int r = 0; r < 32; ++r) {
      float kv = Ks[r][hh * 16 + f];
      float vv = Vs[r][hh * 16 + c];
      float k2 = kv * kv;
      a1 = fmaf(kv, vv, a1);
      a2 = fmaf(k2, vv, a2);
      a3 = fmaf(k2 * kv, vv, a3);
    }
    float* base = sb + (size_t)hh * 832 + f * 16 + c;
    atomicAdd(base, a1);
    atomicAdd(base + 256, a2);
    atomicAdd(base + 512, a3);
  }
  if (tid < 192) {
    int kk = tid >> 6, hf = tid & 63, h2 = hf >> 4, ff = hf & 15;
    float s = 0.f;
    for (int r = 0; r < 32; ++r) {
      float kv = Ks[r][hf];
      s += (kk == 0) ? kv : (kk == 1) ? kv * kv : kv * kv * kv;
    }
    atomicAdd(sb + (size_t)h2 * 832 + 768 + kk * 16 + ff, s);
  } else if (tid < 256) {
    int hf = tid - 192, h2 = hf >> 4;
    float s = 0.f;
    for (int r = 0; r < 32; ++r) s += Vs[r][hf];
    atomicAdd(sb + (size_t)h2 * 832 + 816 + (hf & 15), s);
  }
}

__global__ __launch_bounds__(512, 2) void k_gemm1(
    const int* __restrict__ flag, const void* __restrict__ x,
    const u16* __restrict__ Bs1, const u16* __restrict__ BsKlo,
    const float* __restrict__ bcat,
    u16* __restrict__ C1, float* __restrict__ stats)
{
  __shared__ float xs[32][196];
  __shared__ float Ks[32][65];
  __shared__ float Vs[32][65];
  if (*flag) gemm1_body<true >(x, Bs1, BsKlo, bcat, C1, stats, xs, Ks, Vs);
  else       gemm1_body<false>(x, Bs1, BsKlo, bcat, C1, stats, xs, Ks, Vs);
}

// ---------------- finalize: coefficient matrices (exact sumN1) --------------
template<bool F32>
__device__ void finalize_body(const float* stats, const void* Pi,
                              const void* Wk, const void* bk,
                              const float* xsum, float* M, float* sn1)
{
  const int bh = blockIdx.x, bb = bh >> 2, h = bh & 3, t = threadIdx.x;
  const float* sb = stats + (size_t)bh * 832;
  float* mb = M + (size_t)bh * 784;
  const float inv6 = 1.0f / 6.0f;

  // exact sumN1[f] = xsum[b,:] @ Wk[:, h*16+f] + 4096*bk
  {
    int f = t >> 4, s = t & 15;
    float p = 0.f;
    for (int i = s * 12; i < s * 12 + 12; ++i)
      p += xsum[bb * 192 + i] * ldwf(Wk, i * 64 + h * 16 + f, F32);
    p += __shfl_xor(p, 1, 64);
    p += __shfl_xor(p, 2, 64);
    p += __shfl_xor(p, 4, 64);
    p += __shfl_xor(p, 8, 64);
    if (s == 0) sn1[f] = p + 4096.0f * ldwf(bk, h * 16 + f, F32);
  }
  __syncthreads();

  {
    const int f = t >> 4, c = t & 15;
    #pragma unroll
    for (int k = 0; k < 3; ++k) {
      float fkv = sb[k * 256 + f * 16 + c];
      float sk  = (k == 0) ? sn1[f] : sb[768 + k * 16 + f];
      float pi  = ldwf(Pi, h * 4 + (k + 1), F32);
      mb[k * 256 + f * 16 + c] = fkv / ((sk + 1e-8f) * 4.0f) * pi * inv6;
    }
  }
  if (t < 16) {
    float sv  = sb[816 + t];
    float pi0 = ldwf(Pi, h * 4 + 0, F32);
    mb[768 + t] = sv / (4096.0f + 1e-8f) * pi0 * inv6;
  }
}

__global__ __launch_bounds__(256) void k_finalize(
    const int* __restrict__ flag, const float* __restrict__ stats,
    const void* __restrict__ Pi, const void* __restrict__ Wk,
    const void* __restrict__ bk, const float* __restrict__ xsum,
    float* __restrict__ M)
{
  __shared__ float sn1[16];
  if (*flag) finalize_body<true >(stats, Pi, Wk, bk, xsum, M, sn1);
  else       finalize_body<false>(stats, Pi, Wk, bk, xsum, M, sn1);
}

// ---------------- mid: att + LN + FFN + LN -> res2 ----------------
template<bool F32> __device__ void mid_body(
    const u16* C1, u16* R2,
    const void* W1, const void* b1, const void* W2, const void* b2,
    const void* lng, const void* lnb, const float* Mall,
    float* W1s, float* W2s, float* Ms)
{
  const int tid = threadIdx.x;
  const int grow0 = blockIdx.x * 64;
  const int b = grow0 >> 12;
  const int h = (grow0 & 4095) >> 10;

  for (int i = tid; i < 8192; i += 512) {
    W1s[i] = ldwf(W1, i, F32);
    W2s[i] = ldwf(W2, i, F32);
  }
  {
    const float* Mp = Mall + (size_t)((b << 2) + h) * 784;
    for (int i = tid; i < 784; i += 512) Ms[i] = Mp[i];
  }
  __syncthreads();

  const int ww = tid >> 6, j = tid & 63;
  const int sub = j >> 4, d = j & 15;
  const int gw = grow0 + ww * 8;
  const int n2b = gw & 4095;

  float m1[16], m2[16], m3[16];
  #pragma unroll
  for (int f = 0; f < 16; ++f) {
    m1[f] = Ms[f * 16 + d];
    m2[f] = Ms[256 + f * 16 + d];
    m3[f] = Ms[512 + f * 16 + d];
  }
  const float c0v = Ms[768 + d];

  float att[8];
  #pragma unroll
  for (int r = 0; r < 8; ++r) {
    const int qrow = (((n2b + r) & 1023) << 2) + sub;
    const u16* qp = C1 + ((size_t)(b << 12) + qrow) * 128 + h * 16;
    uint4 qa = *(const uint4*)qp;
    uint4 qb = *(const uint4*)(qp + 8);
    float q[16] = {lo16(qa.x), hi16(qa.x), lo16(qa.y), hi16(qa.y),
                   lo16(qa.z), hi16(qa.z), lo16(qa.w), hi16(qa.w),
                   lo16(qb.x), hi16(qb.x), lo16(qb.y), hi16(qb.y),
                   lo16(qb.z), hi16(qb.z), lo16(qb.w), hi16(qb.w)};
    float a = c0v;
    #pragma unroll
    for (int f = 0; f < 16; ++f) {
      float qv = q[f], q2 = qv * qv;
      a = fmaf(qv, m1[f], a);
      a = fmaf(q2, m2[f], a);
      a = fmaf(q2 * qv, m3[f], a);
    }
    att[r] = a;
  }

  const float gj = ldwf(lng, j, F32), bj = ldwf(lnb, j, F32);
  float res1[8];
  #pragma unroll
  for (int r = 0; r < 8; ++r) {
    float pr = bf2f(C1[(size_t)(gw + r) * 128 + 64 + j]);
    res1[r] = ln64(pr + att[r], gj, bj);
  }

  float h1[8], h2[8];
  {
    float a1 = ldwf(b1, j, F32), a2 = ldwf(b1, j + 64, F32);
    #pragma unroll
    for (int r = 0; r < 8; ++r) { h1[r] = a1; h2[r] = a2; }
  }
  #pragma unroll 4
  for (int i = 0; i < 64; ++i) {
    float w1a = W1s[i * 128 + j];
    float w1b = W1s[i * 128 + 64 + j];
    #pragma unroll
    for (int r = 0; r < 8; ++r) {
      float rv = __shfl(res1[r], i, 64);
      h1[r] = fmaf(rv, w1a, h1[r]);
      h2[r] = fmaf(rv, w1b, h2[r]);
    }
  }
  #pragma unroll
  for (int r = 0; r < 8; ++r) {
    h1[r] = fmaxf(h1[r], 0.f);
    h2[r] = fmaxf(h2[r], 0.f);
  }

  float oo[8];
  {
    float bb = ldwf(b2, j, F32);
    #pragma unroll
    for (int r = 0; r < 8; ++r) oo[r] = bb;
  }
  #pragma unroll 4
  for (int c = 0; c < 64; ++c) {
    float w2a = W2s[c * 64 + j];
    float w2b = W2s[(c + 64) * 64 + j];
    #pragma unroll
    for (int r = 0; r < 8; ++r) {
      oo[r] = fmaf(__shfl(h1[r], c, 64), w2a, oo[r]);
      oo[r] = fmaf(__shfl(h2[r], c, 64), w2b, oo[r]);
    }
  }
  #pragma unroll
  for (int r = 0; r < 8; ++r) {
    float r2 = ln64(res1[r] + oo[r], gj, bj);
    R2[(size_t)(gw + r) * 64 + j] = f2bf(r2);
  }
}

__global__ __launch_bounds__(512, 2) void k_mid(
    const int* __restrict__ flag, const u16* __restrict__ C1,
    u16* __restrict__ R2,
    const void* __restrict__ W1, const void* __restrict__ b1,
    const void* __restrict__ W2, const void* __restrict__ b2,
    const void* __restrict__ lng, const void* __restrict__ lnb,
    const float* __restrict__ Mall)
{
  __shared__ float W1s[8192];
  __shared__ float W2s[8192];
  __shared__ float Ms[784];
  if (*flag) mid_body<true >(C1, R2, W1, b1, W2, b2, lng, lnb, Mall, W1s, W2s, Ms);
  else       mid_body<false>(C1, R2, W1, b1, W2, b2, lng, lnb, Mall, W1s, W2s, Ms);
}

// ---------------- GEMM2: out = [res2|x] @ [Wout;Wp] + bout ----------------
__global__ __launch_bounds__(256, 2) void k_gemm2(
    const int* __restrict__ flag,
    const u16* __restrict__ R2, const u16* __restrict__ xb,
    const u16* __restrict__ Bs2, const void* __restrict__ bout,
    void* __restrict__ out)
{
  const int isf = *flag;
  const int l = threadIdx.x & 63;
  const int w = threadIdx.x >> 6;
  const int mbase = blockIdx.x * 64;
  const int lm = l & 15, lk = l >> 4;

  short8 bf[8][3];
  #pragma unroll
  for (int ks = 0; ks < 8; ++ks)
    #pragma unroll
    for (int nt = 0; nt < 3; ++nt)
      bf[ks][nt] = ld_frag8(Bs2 + (size_t)((ks * 12 + w * 3 + nt) * 64 + l) * 8);

  float bias[3];
  #pragma unroll
  for (int nt = 0; nt < 3; ++nt) bias[nt] = ldwf(bout, w * 48 + nt * 16 + lm, isf);

  short8 af[8];
  {
    const int row = mbase + lm;
    const u16* rp = R2 + (size_t)row * 64 + lk * 8;
    af[0] = ld_frag8(rp);
    af[1] = ld_frag8(rp + 32);
    const u16* xp = xb + (size_t)row * IND + lk * 8;
    #pragma unroll
    for (int ks = 2; ks < 8; ++ks) af[ks] = ld_frag8(xp + (ks - 2) * 32);
  }

  for (int mt = 0; mt < 4; ++mt) {
    short8 afn[8];
    if (mt < 3) {
      const int row = mbase + (mt + 1) * 16 + lm;
      const u16* rp = R2 + (size_t)row * 64 + lk * 8;
      afn[0] = ld_frag8(rp);
      afn[1] = ld_frag8(rp + 32);
      const u16* xp = xb + (size_t)row * IND + lk * 8;
      #pragma unroll
      for (int ks = 2; ks < 8; ++ks) afn[ks] = ld_frag8(xp + (ks - 2) * 32);
    }
    f32x4 acc[3];
    #pragma unroll
    for (int nt = 0; nt < 3; ++nt) {
      f32x4 a = {bias[nt], bias[nt], bias[nt], bias[nt]};
      acc[nt] = a;
    }
    #pragma unroll
    for (int ks = 0; ks < 8; ++ks)
      #pragma unroll
      for (int nt = 0; nt < 3; ++nt)
        acc[nt] = MFMA16(af[ks], bf[ks][nt], acc[nt], 0, 0, 0);
    const int r0 = mbase + mt * 16 + lk * 4;
    const int c0 = w * 48 + lm;
    if (isf) {
      float* op = (float*)out;
      #pragma unroll
      for (int nt = 0; nt < 3; ++nt)
        #pragma unroll
        for (int r = 0; r < 4; ++r)
          op[(size_t)(r0 + r) * IND + c0 + nt * 16] = acc[nt][r];
    } else {
      u16* op = (u16*)out;
      #pragma unroll
      for (int nt = 0; nt < 3; ++nt)
        #pragma unroll
        for (int r = 0; r < 4; ++r)
          op[(size_t)(r0 + r) * IND + c0 + nt * 16] = f2bf(acc[nt][r]);
    }
    #pragma unroll
    for (int ks = 0; ks < 8; ++ks) af[ks] = afn[ks];
  }
}

extern "C" void kernel_launch(void* const* d_in, const int* in_sizes, int n_in,
                              void* d_out, int out_size, void* d_ws, size_t ws_size,
                              hipStream_t stream)
{
  const void* x   = d_in[0];
  const void* Wq  = d_in[1];
  const void* bq  = d_in[2];
  const void* Wk  = d_in[3];
  const void* bk  = d_in[4];
  const void* Wv  = d_in[5];
  const void* bv  = d_in[6];
  const void* Win = d_in[7];
  const void* Wout= d_in[8];
  const void* bout= d_in[9];
  const void* W1  = d_in[10];
  const void* b1  = d_in[11];
  const void* W2  = d_in[12];
  const void* b2  = d_in[13];
  const void* lng = d_in[14];
  const void* lnb = d_in[15];
  const void* Wp  = d_in[16];
  const void* Pi  = d_in[17];

  u16* xb    = (u16*)d_ws;                  // 12,582,912
  u16* C1    = xb + (size_t)12582912;       // 8,388,608  (Q | proj)
  u16* R2    = C1 + (size_t)8388608;        // 4,194,304  (res2)
  u16* Bs1   = R2 + (size_t)4194304;        // 49,152
  u16* BsKlo = Bs1 + 49152;                 // 12,288
  u16* Bs2   = BsKlo + 12288;               // 49,152
  float* bcat  = (float*)(Bs2 + 49152);     // 256
  float* stats = bcat + 256;                // 53,248
  float* xsum  = stats + 53248;             // 3,072
  float* Mc    = xsum + 3072;               // 50,176
  int*   flag  = (int*)(Mc + 50176);

  k_detect<<<1, 64, 0, stream>>>((const u32*)x, flag);
  hipMemsetAsync(stats, 0, (size_t)(53248 + 3072) * sizeof(float), stream);

  k_prepw<<<433, 256, 0, stream>>>(flag, Wq, Wk, Wv, Win, Wout, Wp,
                                   bq, bk, bv, Bs1, BsKlo, Bs2, bcat);
  k_xb<<<4096, 256, 0, stream>>>(flag, x, xb);
  k_xsum<<<256, 192, 0, stream>>>(flag, x, xsum);
  k_gemm1<<<2048, 512, 0, stream>>>(flag, x, Bs1, BsKlo, bcat, C1, stats);
  k_finalize<<<64, 256, 0, stream>>>(flag, stats, Pi, Wk, bk, xsum, Mc);
  k_mid<<<1024, 512, 0, stream>>>(flag, C1, R2, W1, b1, W2, b2, lng, lnb, Mc);
  k_gemm2<<<1024, 256, 0, stream>>>(flag, R2, xb, Bs2, bout, d_out);
}

// Round 6
// 161.805 us; speedup vs baseline: 3.6379x; 1.8243x over previous
//
#include <hip/hip_runtime.h>

typedef unsigned int u32;
typedef unsigned short u16;

#define NB 16
#define NN 4096
#define IND 192

typedef __attribute__((ext_vector_type(8))) short short8;
typedef __attribute__((ext_vector_type(4))) float f32x4;
#define MFMA16 __builtin_amdgcn_mfma_f32_16x16x32_bf16

__device__ __forceinline__ float bf2f(u16 u) {
  union { u32 i; float f; } c; c.i = ((u32)u) << 16; return c.f;
}
__device__ __forceinline__ float lo16(u32 u) {
  union { u32 i; float f; } c; c.i = u << 16; return c.f;
}
__device__ __forceinline__ float hi16(u32 u) {
  union { u32 i; float f; } c; c.i = u & 0xffff0000u; return c.f;
}
__device__ __forceinline__ u16 f2bf(float f) {
  union { float f; u32 i; } c; c.f = f;
  u32 r = c.i + 0x7fffu + ((c.i >> 16) & 1u);  // RNE
  return (u16)(r >> 16);
}
__device__ __forceinline__ float ldwf(const void* p, int i, int isf) {
  return isf ? ((const float*)p)[i] : bf2f(((const u16*)p)[i]);
}
__device__ __forceinline__ short8 ld_frag8(const u16* p) {
  union { uint4 u; short8 s; } c;
  c.u = *reinterpret_cast<const uint4*>(p);
  return c.s;
}
__device__ __forceinline__ short8 as_short8(uint4 u) {
  union { uint4 u; short8 s; } c; c.u = u; return c.s;
}
__device__ __forceinline__ short8 pack8(const float* v) {
  short8 s;
  #pragma unroll
  for (int e = 0; e < 8; ++e) s[e] = (short)f2bf(v[e]);
  return s;
}
__device__ __forceinline__ float ln64(float y, float g, float be) {
  float s = y, sq = y * y;
  #pragma unroll
  for (int off = 32; off > 0; off >>= 1) {
    s  += __shfl_xor(s, off, 64);
    sq += __shfl_xor(sq, off, 64);
  }
  float mu  = s * 0.015625f;
  float var = sq * 0.015625f - mu * mu;
  return (y - mu) * rsqrtf(var + 1e-5f) * g + be;
}

// ---------------- dtype detect ----------------
__global__ __launch_bounds__(64) void k_detect(const u32* __restrict__ x2,
                                               int* __restrict__ flag) {
  int t = threadIdx.x;
  int bad = 0;
  for (int i = 0; i < 16; ++i) {
    float a = fabsf(lo16(x2[t * 16 + i]));
    if (!(a < 1e4f)) bad = 1;
  }
  int anybad = __any(bad);
  if (t == 0) *flag = anybad ? 1 : 0;   // 1 = fp32 inputs
}

// ---------------- x -> bf16 ----------------
__global__ __launch_bounds__(256) void k_xb(const int* __restrict__ flag,
                                            const void* __restrict__ x,
                                            u16* __restrict__ xb) {
  const int isf = *flag;
  size_t gid = (size_t)blockIdx.x * 256 + threadIdx.x;
  if (isf) {
    const float4* src = (const float4*)x;
    for (size_t i = gid; i < 3145728; i += 1048576) {
      float4 v = src[i];
      ushort4 o;
      o.x = f2bf(v.x); o.y = f2bf(v.y); o.z = f2bf(v.z); o.w = f2bf(v.w);
      ((ushort4*)xb)[i] = o;
    }
  } else {
    const uint4* src = (const uint4*)x;
    for (size_t i = gid; i < 1572864; i += 1048576)
      ((uint4*)xb)[i] = src[i];
  }
}

// ---------------- per-batch column sums of x (fp32 exact) ----------------
__global__ __launch_bounds__(192) void k_xsum(const int* __restrict__ flag,
                                              const void* __restrict__ x,
                                              float* __restrict__ xsum) {
  const int isf = *flag;
  const int t = threadIdx.x;
  const int r0 = blockIdx.x * 256;
  const int b = r0 >> 12;
  float s = 0.f;
  if (isf) {
    const float* xp = (const float*)x;
    for (int r = 0; r < 256; ++r) s += xp[(size_t)(r0 + r) * 192 + t];
  } else {
    const u16* xp = (const u16*)x;
    for (int r = 0; r < 256; ++r) s += bf2f(xp[(size_t)(r0 + r) * 192 + t]);
  }
  atomicAdd(xsum + b * 192 + t, s);
}

// ---------------- build swizzled B operands ----------------
// Bs1:   [ks(6)][nt(16)][l(64)][e(8)]  over [Wq|Wk|Wv|Win] (192x256)
// BsKlo: [ks(6)][nt'(4)][l(64)][e(8)]  Wk lo-part
// Bs2:   [ks(8)][nt(12)][l(64)][e(8)]  over [Wout;Wp] (256x192)
// W1f:   [ks(2)][nt(8)][l(64)][e(8)]   W1 (64x128)
// W2f:   [ks(4)][nt(4)][l(64)][e(8)]   W2 (128x64)
__global__ __launch_bounds__(256) void k_prepw(
    const int* __restrict__ flag,
    const void* Wq, const void* Wk, const void* Wv, const void* Win,
    const void* Wout, const void* Wp, const void* W1, const void* W2,
    const void* bq, const void* bk, const void* bv,
    u16* __restrict__ Bs1, u16* __restrict__ BsKlo, u16* __restrict__ Bs2,
    u16* __restrict__ W1f, u16* __restrict__ W2f, float* __restrict__ bcat)
{
  const int isf = *flag;
  int idx = blockIdx.x * 256 + threadIdx.x;
  if (idx < 49152) {
    int e = idx & 7, l = (idx >> 3) & 63, g = idx >> 9;
    int nt = g & 15, ks = g >> 4;
    int k = ks * 32 + (l >> 4) * 8 + e;
    int n = nt * 16 + (l & 15);
    const void* W = (n < 64) ? Wq : (n < 128) ? Wk : (n < 192) ? Wv : Win;
    Bs1[idx] = f2bf(ldwf(W, k * 64 + (n & 63), isf));
  } else if (idx < 61440) {
    int j = idx - 49152;
    int e = j & 7, l = (j >> 3) & 63, g = j >> 9;
    int ntp = g & 3, ks = g >> 2;
    int k = ks * 32 + (l >> 4) * 8 + e;
    int n = ntp * 16 + (l & 15);
    float wv = ldwf(Wk, k * 64 + n, isf);
    u16 hi = f2bf(wv);
    BsKlo[j] = f2bf(wv - bf2f(hi));
  } else if (idx < 110592) {
    int j = idx - 61440;
    int e = j & 7, l = (j >> 3) & 63, g = j >> 9;
    int nt = g % 12, ks = g / 12;
    int k = ks * 32 + (l >> 4) * 8 + e;
    int n = nt * 16 + (l & 15);
    float v = (k < 64) ? ldwf(Wout, k * 192 + n, isf)
                       : ldwf(Wp, (k - 64) * 192 + n, isf);
    Bs2[j] = f2bf(v);
  } else if (idx < 118784) {
    int j = idx - 110592;
    int e = j & 7, l = (j >> 3) & 63, g = j >> 9;   // 0..15
    int nt = g & 7, ks = g >> 3;
    int k = ks * 32 + (l >> 4) * 8 + e;
    int n = nt * 16 + (l & 15);
    W1f[j] = f2bf(ldwf(W1, k * 128 + n, isf));
  } else if (idx < 126976) {
    int j = idx - 118784;
    int e = j & 7, l = (j >> 3) & 63, g = j >> 9;   // 0..15
    int nt = g & 3, ks = g >> 2;
    int k = ks * 32 + (l >> 4) * 8 + e;
    int n = nt * 16 + (l & 15);
    W2f[j] = f2bf(ldwf(W2, k * 64 + n, isf));
  } else if (idx < 127232) {
    int n = idx - 126976;
    bcat[n] = (n < 64)  ? ldwf(bq, n, isf)
            : (n < 128) ? ldwf(bk, n - 64, isf)
            : (n < 192) ? ldwf(bv, n - 128, isf) : 0.f;
  }
}

// ---------------- GEMM1 fused with stats ----------
template<bool F32>
__device__ void gemm1_body(const void* __restrict__ x,
                           const u16* __restrict__ Bs1,
                           const u16* __restrict__ BsKlo,
                           const float* __restrict__ bcat,
                           u16* __restrict__ C1, float* __restrict__ stats,
                           float (*xs)[196], float (*Ks)[65], float (*Vs)[65])
{
  const int tid = threadIdx.x;
  const int mbase = blockIdx.x * 32;
  const int b = mbase >> 12;

  if constexpr (F32) {
    for (int i = tid; i < 1536; i += 512) {
      int row = i / 48, c4 = i - row * 48;
      float4 v = *((const float4*)x + (size_t)(mbase + row) * 48 + c4);
      *(float4*)&xs[row][c4 * 4] = v;
    }
  } else {
    for (int i = tid; i < 768; i += 512) {
      int row = i / 24, c8 = i - row * 24;
      uint4 v = *((const uint4*)x + (size_t)(mbase + row) * 24 + c8);
      float* dst = &xs[row][c8 * 8];
      dst[0]=lo16(v.x); dst[1]=hi16(v.x); dst[2]=lo16(v.y); dst[3]=hi16(v.y);
      dst[4]=lo16(v.z); dst[5]=hi16(v.z); dst[6]=lo16(v.w); dst[7]=hi16(v.w);
    }
  }
  __syncthreads();

  const int w = tid >> 6, l = tid & 63, lm = l & 15, lk = l >> 4;
  const int nt0 = w * 2;
  const bool isK = (w == 2) || (w == 3);

  short8 bhi[2][6], blo[2][6];
  #pragma unroll
  for (int n2 = 0; n2 < 2; ++n2)
    #pragma unroll
    for (int ks = 0; ks < 6; ++ks) {
      bhi[n2][ks] = ld_frag8(Bs1 + (size_t)((ks * 16 + nt0 + n2) * 64 + l) * 8);
      if (F32 && isK)
        blo[n2][ks] = ld_frag8(BsKlo + (size_t)((ks * 4 + nt0 + n2 - 4) * 64 + l) * 8);
    }
  float bias[2];
  bias[0] = bcat[nt0 * 16 + lm];
  bias[1] = bcat[(nt0 + 1) * 16 + lm];

  for (int mt = 0; mt < 2; ++mt) {
    short8 ahi[6], alo[6];
    const float* xr = &xs[mt * 16 + lm][0];
    #pragma unroll
    for (int ks = 0; ks < 6; ++ks) {
      float v[8];
      *(float4*)&v[0] = *(const float4*)(xr + ks * 32 + lk * 8);
      *(float4*)&v[4] = *(const float4*)(xr + ks * 32 + lk * 8 + 4);
      short8 h8;
      #pragma unroll
      for (int e = 0; e < 8; ++e) h8[e] = (short)f2bf(v[e]);
      ahi[ks] = h8;
      if (F32 && isK) {
        short8 l8;
        #pragma unroll
        for (int e = 0; e < 8; ++e) {
          float r = v[e] - bf2f((u16)h8[e]);
          l8[e] = (short)f2bf(r);
        }
        alo[ks] = l8;
      }
    }
    f32x4 acc[2];
    #pragma unroll
    for (int n2 = 0; n2 < 2; ++n2) {
      f32x4 a = {bias[n2], bias[n2], bias[n2], bias[n2]};
      acc[n2] = a;
    }
    #pragma unroll
    for (int ks = 0; ks < 6; ++ks)
      #pragma unroll
      for (int n2 = 0; n2 < 2; ++n2) {
        acc[n2] = MFMA16(ahi[ks], bhi[n2][ks], acc[n2], 0, 0, 0);
        if (F32 && isK) {
          acc[n2] = MFMA16(ahi[ks], blo[n2][ks], acc[n2], 0, 0, 0);
          acc[n2] = MFMA16(alo[ks], bhi[n2][ks], acc[n2], 0, 0, 0);
          acc[n2] = MFMA16(alo[ks], blo[n2][ks], acc[n2], 0, 0, 0);
        }
      }
    const int rl = mt * 16 + lk * 4;
    if (w < 2) {
      #pragma unroll
      for (int n2 = 0; n2 < 2; ++n2)
        #pragma unroll
        for (int r = 0; r < 4; ++r)
          C1[(size_t)(mbase + rl + r) * 128 + (nt0 + n2) * 16 + lm] = f2bf(acc[n2][r]);
    } else if (isK) {
      #pragma unroll
      for (int n2 = 0; n2 < 2; ++n2)
        #pragma unroll
        for (int r = 0; r < 4; ++r)
          Ks[rl + r][(nt0 + n2 - 4) * 16 + lm] = acc[n2][r];
    } else if (w < 6) {
      #pragma unroll
      for (int n2 = 0; n2 < 2; ++n2)
        #pragma unroll
        for (int r = 0; r < 4; ++r)
          Vs[rl + r][(nt0 + n2 - 8) * 16 + lm] = acc[n2][r];
    } else {
      #pragma unroll
      for (int n2 = 0; n2 < 2; ++n2)
        #pragma unroll
        for (int r = 0; r < 4; ++r)
          C1[(size_t)(mbase + rl + r) * 128 + 64 + (nt0 + n2 - 12) * 16 + lm] = f2bf(acc[n2][r]);
    }
  }
  __syncthreads();

  float* sb = stats + (size_t)(b * 4) * 832;
  #pragma unroll
  for (int it = 0; it < 2; ++it) {
    int item = tid + it * 512;
    int hh = item >> 8, f = (item >> 4) & 15, c = item & 15;
    float a1 = 0.f, a2 = 0.f, a3 = 0.f;
    for (int r = 0; r < 32; ++r) {
      float kv = Ks[r][hh * 16 + f];
      float vv = Vs[r][hh * 16 + c];
      float k2 = kv * kv;
      a1 = fmaf(kv, vv, a1);
      a2 = fmaf(k2, vv, a2);
      a3 = fmaf(k2 * kv, vv, a3);
    }
    float* base = sb + (size_t)hh * 832 + f * 16 + c;
    atomicAdd(base, a1);
    atomicAdd(base + 256, a2);
    atomicAdd(base + 512, a3);
  }
  if (tid < 192) {
    int kk = tid >> 6, hf = tid & 63, h2 = hf >> 4, ff = hf & 15;
    float s = 0.f;
    for (int r = 0; r < 32; ++r) {
      float kv = Ks[r][hf];
      s += (kk == 0) ? kv : (kk == 1) ? kv * kv : kv * kv * kv;
    }
    atomicAdd(sb + (size_t)h2 * 832 + 768 + kk * 16 + ff, s);
  } else if (tid < 256) {
    int hf = tid - 192, h2 = hf >> 4;
    float s = 0.f;
    for (int r = 0; r < 32; ++r) s += Vs[r][hf];
    atomicAdd(sb + (size_t)h2 * 832 + 816 + (hf & 15), s);
  }
}

__global__ __launch_bounds__(512, 2) void k_gemm1(
    const int* __restrict__ flag, const void* __restrict__ x,
    const u16* __restrict__ Bs1, const u16* __restrict__ BsKlo,
    const float* __restrict__ bcat,
    u16* __restrict__ C1, float* __restrict__ stats)
{
  __shared__ float xs[32][196];
  __shared__ float Ks[32][65];
  __shared__ float Vs[32][65];
  if (*flag) gemm1_body<true >(x, Bs1, BsKlo, bcat, C1, stats, xs, Ks, Vs);
  else       gemm1_body<false>(x, Bs1, BsKlo, bcat, C1, stats, xs, Ks, Vs);
}

// ---------------- finalize (exact sumN1 via xsum) ----------------
template<bool F32>
__device__ void finalize_body(const float* stats, const void* Pi,
                              const void* Wk, const void* bk,
                              const float* xsum, float* M, float* sn1)
{
  const int bh = blockIdx.x, bb = bh >> 2, h = bh & 3, t = threadIdx.x;
  const float* sb = stats + (size_t)bh * 832;
  float* mb = M + (size_t)bh * 784;
  const float inv6 = 1.0f / 6.0f;

  {
    int f = t >> 4, s = t & 15;
    float p = 0.f;
    for (int i = s * 12; i < s * 12 + 12; ++i)
      p += xsum[bb * 192 + i] * ldwf(Wk, i * 64 + h * 16 + f, F32);
    p += __shfl_xor(p, 1, 64);
    p += __shfl_xor(p, 2, 64);
    p += __shfl_xor(p, 4, 64);
    p += __shfl_xor(p, 8, 64);
    if (s == 0) sn1[f] = p + 4096.0f * ldwf(bk, h * 16 + f, F32);
  }
  __syncthreads();

  {
    const int f = t >> 4, c = t & 15;
    #pragma unroll
    for (int k = 0; k < 3; ++k) {
      float fkv = sb[k * 256 + f * 16 + c];
      float sk  = (k == 0) ? sn1[f] : sb[768 + k * 16 + f];
      float pi  = ldwf(Pi, h * 4 + (k + 1), F32);
      mb[k * 256 + f * 16 + c] = fkv / ((sk + 1e-8f) * 4.0f) * pi * inv6;
    }
  }
  if (t < 16) {
    float sv  = sb[816 + t];
    float pi0 = ldwf(Pi, h * 4 + 0, F32);
    mb[768 + t] = sv / (4096.0f + 1e-8f) * pi0 * inv6;
  }
}

__global__ __launch_bounds__(256) void k_finalize(
    const int* __restrict__ flag, const float* __restrict__ stats,
    const void* __restrict__ Pi, const void* __restrict__ Wk,
    const void* __restrict__ bk, const float* __restrict__ xsum,
    float* __restrict__ M)
{
  __shared__ float sn1[16];
  if (*flag) finalize_body<true >(stats, Pi, Wk, bk, xsum, M, sn1);
  else       finalize_body<false>(stats, Pi, Wk, bk, xsum, M, sn1);
}

// ---------------- mid v2: MFMA att + LN + MFMA FFN + LN ----------------
// 1024 blocks x 256 thr (4 waves). Block = 64 output rows, fixed (b,h).
// Wave w owns rows w*16..w*16+15 through ALL phases -> no barriers.
template<bool F32> __device__ void mid_body(
    const u16* __restrict__ C1, u16* __restrict__ R2,
    const float* __restrict__ Mall,
    const u16* __restrict__ W1f, const u16* __restrict__ W2f,
    const void* __restrict__ b1, const void* __restrict__ b2,
    const void* __restrict__ lng, const void* __restrict__ lnb,
    float (*attL)[72], u16 (*resB)[72], u16 (*hB)[136])
{
  const int tid = threadIdx.x;
  const int w = tid >> 6, l = tid & 63;
  const int lm = l & 15, lk = l >> 4;
  const int n0g = blockIdx.x * 64;                 // global out-row base
  const int b = n0g >> 12;
  const int n2_0 = n0g & 4095;
  const int h = n2_0 >> 10;
  const int qg0 = (b << 12) + ((n2_0 & 1023) << 2);  // global Q-row base
  const float* mb = Mall + (size_t)((b << 2) + h) * 784;

  // ---- phase 1: att via MFMA ----
  short8 Bhi[2], Blo[2];
  #pragma unroll
  for (int ks = 0; ks < 2; ++ks) {
    float vh[8], vl[8];
    #pragma unroll
    for (int e = 0; e < 8; ++e) {
      int kk = ks * 32 + lk * 8 + e;
      float v = (kk < 16) ? mb[kk * 16 + lm]
              : (kk < 32) ? mb[256 + (kk - 16) * 16 + lm]
              : (kk < 48) ? mb[512 + (kk - 32) * 16 + lm] : 0.f;
      float hi = bf2f(f2bf(v));
      vh[e] = hi; vl[e] = v - hi;
    }
    Bhi[ks] = pack8(vh);
    Blo[ks] = pack8(vl);
  }
  const float c0v = mb[768 + lm];

  #pragma unroll
  for (int mt2 = 0; mt2 < 4; ++mt2) {
    const int mt = w * 4 + mt2;
    uint4 qv = *(const uint4*)(C1 + (size_t)(qg0 + mt * 16 + lm) * 128
                               + h * 16 + (lk & 1) * 8);
    float q[8] = {lo16(qv.x), hi16(qv.x), lo16(qv.y), hi16(qv.y),
                  lo16(qv.z), hi16(qv.z), lo16(qv.w), hi16(qv.w)};
    float q2[8], q3[8];
    #pragma unroll
    for (int e = 0; e < 8; ++e) { q2[e] = q[e] * q[e]; q3[e] = q2[e] * q[e]; }
    short8 a1, a2;
    if (lk < 2) { a1 = as_short8(qv); a2 = pack8(q3); }
    else        { a1 = pack8(q2);     a2 = short8{0,0,0,0,0,0,0,0}; }

    f32x4 acc = {c0v, c0v, c0v, c0v};
    acc = MFMA16(a1, Bhi[0], acc, 0, 0, 0);
    acc = MFMA16(a1, Blo[0], acc, 0, 0, 0);
    acc = MFMA16(a2, Bhi[1], acc, 0, 0, 0);
    acc = MFMA16(a2, Blo[1], acc, 0, 0, 0);

    #pragma unroll
    for (int r = 0; r < 4; ++r) {
      int qr = mt * 16 + lk * 4 + r;       // local Q-row 0..255
      attL[qr >> 2][(qr & 3) * 16 + lm] = acc[r];
    }
  }

  // ---- phase 2: proj + att -> LN -> res1 (bf16 in LDS) ----
  const float gj = ldwf(lng, l, F32), bj = ldwf(lnb, l, F32);
  #pragma unroll 4
  for (int rr = 0; rr < 16; ++rr) {
    int r = w * 16 + rr;
    float proj = bf2f(C1[(size_t)(n0g + r) * 128 + 64 + l]);
    float y = proj + attL[r][l];
    resB[r][l] = f2bf(ln64(y, gj, bj));
  }

  // ---- phase 3: FFN1 via MFMA ----
  short8 a0 = *(const short8*)&resB[w * 16 + lm][lk * 8];
  short8 a1f = *(const short8*)&resB[w * 16 + lm][32 + lk * 8];
  f32x4 hacc[8];
  #pragma unroll
  for (int nt = 0; nt < 8; ++nt) {
    float bv = ldwf(b1, nt * 16 + lm, F32);
    f32x4 a = {bv, bv, bv, bv};
    hacc[nt] = a;
  }
  #pragma unroll
  for (int nt = 0; nt < 8; ++nt) {
    short8 w1a = ld_frag8(W1f + (size_t)((0 * 8 + nt) * 64 + l) * 8);
    short8 w1b = ld_frag8(W1f + (size_t)((1 * 8 + nt) * 64 + l) * 8);
    hacc[nt] = MFMA16(a0, w1a, hacc[nt], 0, 0, 0);
    hacc[nt] = MFMA16(a1f, w1b, hacc[nt], 0, 0, 0);
  }
  #pragma unroll
  for (int nt = 0; nt < 8; ++nt)
    #pragma unroll
    for (int r = 0; r < 4; ++r) {
      int row = w * 16 + lk * 4 + r;
      hB[row][nt * 16 + lm] = f2bf(fmaxf(hacc[nt][r], 0.f));
    }

  // ---- phase 4: FFN2 via MFMA ----
  short8 ha[4];
  #pragma unroll
  for (int ks = 0; ks < 4; ++ks)
    ha[ks] = *(const short8*)&hB[w * 16 + lm][ks * 32 + lk * 8];
  f32x4 oacc[4];
  #pragma unroll
  for (int nt = 0; nt < 4; ++nt) {
    float bv = ldwf(b2, nt * 16 + lm, F32);
    f32x4 a = {bv, bv, bv, bv};
    oacc[nt] = a;
  }
  #pragma unroll
  for (int ks = 0; ks < 4; ++ks)
    #pragma unroll
    for (int nt = 0; nt < 4; ++nt) {
      short8 w2v = ld_frag8(W2f + (size_t)((ks * 4 + nt) * 64 + l) * 8);
      oacc[nt] = MFMA16(ha[ks], w2v, oacc[nt], 0, 0, 0);
    }

  // ---- phase 5: residual + LN2 on C-layout, write R2 ----
  float gcol[4], bcol[4];
  #pragma unroll
  for (int nt = 0; nt < 4; ++nt) {
    gcol[nt] = ldwf(lng, nt * 16 + lm, F32);
    bcol[nt] = ldwf(lnb, nt * 16 + lm, F32);
  }
  #pragma unroll
  for (int r = 0; r < 4; ++r) {
    int row = w * 16 + lk * 4 + r;
    float y[4];
    float s = 0.f, sq = 0.f;
    #pragma unroll
    for (int nt = 0; nt < 4; ++nt) {
      y[nt] = oacc[nt][r] + bf2f(resB[row][nt * 16 + lm]);
      s += y[nt];
      sq = fmaf(y[nt], y[nt], sq);
    }
    #pragma unroll
    for (int off = 8; off > 0; off >>= 1) {
      s  += __shfl_xor(s, off, 64);
      sq += __shfl_xor(sq, off, 64);
    }
    float mu = s * 0.015625f;
    float var = sq * 0.015625f - mu * mu;
    float rs = rsqrtf(var + 1e-5f);
    #pragma unroll
    for (int nt = 0; nt < 4; ++nt) {
      float r2v = (y[nt] - mu) * rs * gcol[nt] + bcol[nt];
      R2[(size_t)(n0g + row) * 64 + nt * 16 + lm] = f2bf(r2v);
    }
  }
}

__global__ __launch_bounds__(256, 2) void k_mid(
    const int* __restrict__ flag, const u16* __restrict__ C1,
    u16* __restrict__ R2, const float* __restrict__ Mall,
    const u16* __restrict__ W1f, const u16* __restrict__ W2f,
    const void* __restrict__ b1, const void* __restrict__ b2,
    const void* __restrict__ lng, const void* __restrict__ lnb)
{
  __shared__ float attL[64][72];
  __shared__ u16 resB[64][72];
  __shared__ u16 hB[64][136];
  if (*flag) mid_body<true >(C1, R2, Mall, W1f, W2f, b1, b2, lng, lnb, attL, resB, hB);
  else       mid_body<false>(C1, R2, Mall, W1f, W2f, b1, b2, lng, lnb, attL, resB, hB);
}

// ---------------- GEMM2: out = [res2|x] @ [Wout;Wp] + bout ----------------
__global__ __launch_bounds__(256, 2) void k_gemm2(
    const int* __restrict__ flag,
    const u16* __restrict__ R2, const u16* __restrict__ xb,
    const u16* __restrict__ Bs2, const void* __restrict__ bout,
    void* __restrict__ out)
{
  const int isf = *flag;
  const int l = threadIdx.x & 63;
  const int w = threadIdx.x >> 6;
  const int mbase = blockIdx.x * 64;
  const int lm = l & 15, lk = l >> 4;

  short8 bf[8][3];
  #pragma unroll
  for (int ks = 0; ks < 8; ++ks)
    #pragma unroll
    for (int nt = 0; nt < 3; ++nt)
      bf[ks][nt] = ld_frag8(Bs2 + (size_t)((ks * 12 + w * 3 + nt) * 64 + l) * 8);

  float bias[3];
  #pragma unroll
  for (int nt = 0; nt < 3; ++nt) bias[nt] = ldwf(bout, w * 48 + nt * 16 + lm, isf);

  short8 af[8];
  {
    const int row = mbase + lm;
    const u16* rp = R2 + (size_t)row * 64 + lk * 8;
    af[0] = ld_frag8(rp);
    af[1] = ld_frag8(rp + 32);
    const u16* xp = xb + (size_t)row * IND + lk * 8;
    #pragma unroll
    for (int ks = 2; ks < 8; ++ks) af[ks] = ld_frag8(xp + (ks - 2) * 32);
  }

  for (int mt = 0; mt < 4; ++mt) {
    short8 afn[8];
    if (mt < 3) {
      const int row = mbase + (mt + 1) * 16 + lm;
      const u16* rp = R2 + (size_t)row * 64 + lk * 8;
      afn[0] = ld_frag8(rp);
      afn[1] = ld_frag8(rp + 32);
      const u16* xp = xb + (size_t)row * IND + lk * 8;
      #pragma unroll
      for (int ks = 2; ks < 8; ++ks) afn[ks] = ld_frag8(xp + (ks - 2) * 32);
    }
    f32x4 acc[3];
    #pragma unroll
    for (int nt = 0; nt < 3; ++nt) {
      f32x4 a = {bias[nt], bias[nt], bias[nt], bias[nt]};
      acc[nt] = a;
    }
    #pragma unroll
    for (int ks = 0; ks < 8; ++ks)
      #pragma unroll
      for (int nt = 0; nt < 3; ++nt)
        acc[nt] = MFMA16(af[ks], bf[ks][nt], acc[nt], 0, 0, 0);
    const int r0 = mbase + mt * 16 + lk * 4;
    const int c0 = w * 48 + lm;
    if (isf) {
      float* op = (float*)out;
      #pragma unroll
      for (int nt = 0; nt < 3; ++nt)
        #pragma unroll
        for (int r = 0; r < 4; ++r)
          op[(size_t)(r0 + r) * IND + c0 + nt * 16] = acc[nt][r];
    } else {
      u16* op = (u16*)out;
      #pragma unroll
      for (int nt = 0; nt < 3; ++nt)
        #pragma unroll
        for (int r = 0; r < 4; ++r)
          op[(size_t)(r0 + r) * IND + c0 + nt * 16] = f2bf(acc[nt][r]);
    }
    #pragma unroll
    for (int ks = 0; ks < 8; ++ks) af[ks] = afn[ks];
  }
}

extern "C" void kernel_launch(void* const* d_in, const int* in_sizes, int n_in,
                              void* d_out, int out_size, void* d_ws, size_t ws_size,
                              hipStream_t stream)
{
  const void* x   = d_in[0];
  const void* Wq  = d_in[1];
  const void* bq  = d_in[2];
  const void* Wk  = d_in[3];
  const void* bk  = d_in[4];
  const void* Wv  = d_in[5];
  const void* bv  = d_in[6];
  const void* Win = d_in[7];
  const void* Wout= d_in[8];
  const void* bout= d_in[9];
  const void* W1  = d_in[10];
  const void* b1  = d_in[11];
  const void* W2  = d_in[12];
  const void* b2  = d_in[13];
  const void* lng = d_in[14];
  const void* lnb = d_in[15];
  const void* Wp  = d_in[16];
  const void* Pi  = d_in[17];

  u16* xb    = (u16*)d_ws;                  // 12,582,912
  u16* C1    = xb + (size_t)12582912;       // 8,388,608  (Q | proj)
  u16* R2    = C1 + (size_t)8388608;        // 4,194,304  (res2)
  u16* Bs1   = R2 + (size_t)4194304;        // 49,152
  u16* BsKlo = Bs1 + 49152;                 // 12,288
  u16* Bs2   = BsKlo + 12288;               // 49,152
  u16* W1f   = Bs2 + 49152;                 // 8,192
  u16* W2f   = W1f + 8192;                  // 8,192
  float* bcat  = (float*)(W2f + 8192);      // 256
  float* stats = bcat + 256;                // 53,248
  float* xsum  = stats + 53248;             // 3,072
  float* Mc    = xsum + 3072;               // 50,176
  int*   flag  = (int*)(Mc + 50176);

  k_detect<<<1, 64, 0, stream>>>((const u32*)x, flag);
  hipMemsetAsync(stats, 0, (size_t)(53248 + 3072) * sizeof(float), stream);

  k_prepw<<<497, 256, 0, stream>>>(flag, Wq, Wk, Wv, Win, Wout, Wp, W1, W2,
                                   bq, bk, bv, Bs1, BsKlo, Bs2, W1f, W2f, bcat);
  k_xb<<<4096, 256, 0, stream>>>(flag, x, xb);
  k_xsum<<<256, 192, 0, stream>>>(flag, x, xsum);
  k_gemm1<<<2048, 512, 0, stream>>>(flag, x, Bs1, BsKlo, bcat, C1, stats);
  k_finalize<<<64, 256, 0, stream>>>(flag, stats, Pi, Wk, bk, xsum, Mc);
  k_mid<<<1024, 256, 0, stream>>>(flag, C1, R2, Mc, W1f, W2f, b1, b2, lng, lnb);
  k_gemm2<<<1024, 256, 0, stream>>>(flag, R2, xb, Bs2, bout, d_out);
}